// Round 1
// baseline (154.938 us; speedup 1.0000x reference)
//
#include <hip/hip_runtime.h>

#define D_DIM   256
#define CHUNK   128
#define WID     33
#define CEN     16

__global__ __launch_bounds__(256) void local_enc_kernel(
    const float* __restrict__ x,
    const float* __restrict__ sizev,
    const float* __restrict__ sm,
    float* __restrict__ out,
    int N)
{
    const int d  = threadIdx.x;          // 0..255, one column per thread
    const int b  = blockIdx.y;
    const int n0 = blockIdx.x * CHUNK;

    const size_t bN = (size_t)b * (size_t)N;
    const float* __restrict__ xb = x   + bN * D_DIM + d;
    float*       __restrict__ ob = out + bN * D_DIM + d;
    const float* __restrict__ smrow = sm    + (bN + (size_t)n0) * WID;  // wave-uniform
    const float* __restrict__ szrow = sizev +  bN + (size_t)n0;         // wave-uniform

    // init sliding window: win[i] = x[b, n0 + i - CEN, d] (0 if OOB)
    float win[WID];
#pragma unroll
    for (int i = 0; i < WID; ++i) {
        int pos = n0 + i - CEN;
        win[i] = (pos >= 0 && pos < N) ? xb[(size_t)pos * D_DIM] : 0.0f;
    }

    for (int j = 0; j < CHUNK; ++j) {
        const int n = n0 + j;

        // weights for this row: wave-uniform address -> scalar loads
        float wv[WID];
#pragma unroll
        for (int i = 0; i < WID; ++i) wv[i] = smrow[j * WID + i];

        float acc = 0.0f;
#pragma unroll
        for (int i = 0; i < WID; ++i) acc += win[i] * wv[i];

        const float inv = 1.0f / fmaxf(szrow[j], 1e-6f);
        ob[(size_t)n * D_DIM] = acc * inv;

        // slide window by one row
#pragma unroll
        for (int i = 0; i < WID - 1; ++i) win[i] = win[i + 1];
        const int pos = n + CEN + 1;                  // always >= 17
        win[WID - 1] = (pos < N) ? xb[(size_t)pos * D_DIM] : 0.0f;
    }
}

extern "C" void kernel_launch(void* const* d_in, const int* in_sizes, int n_in,
                              void* d_out, int out_size, void* d_ws, size_t ws_size,
                              hipStream_t stream) {
    const float* x  = (const float*)d_in[0];
    const float* sz = (const float*)d_in[1];
    const float* sm = (const float*)d_in[2];
    float* out = (float*)d_out;

    const int B = 8;
    const int N = 16384;

    dim3 grid(N / CHUNK, B, 1);
    dim3 block(D_DIM, 1, 1);
    local_enc_kernel<<<grid, block, 0, stream>>>(x, sz, sm, out, N);
}

// Round 2
// 131.136 us; speedup vs baseline: 1.1815x; 1.1815x over previous
//
#include <hip/hip_runtime.h>

#define D_DIM   256
#define WID     33
#define CEN     16
#define CHUNK   66          // 2 * WID — keeps rotation index compile-time

__global__ __launch_bounds__(256) void local_enc_kernel(
    const float* __restrict__ x,
    const float* __restrict__ sizev,
    const float* __restrict__ sm,
    float* __restrict__ out,
    int N)
{
    const int d  = threadIdx.x;          // one column per thread
    const int b  = blockIdx.y;
    const int n0 = blockIdx.x * CHUNK;

    const size_t bN = (size_t)b * (size_t)N;
    const float* __restrict__ xb  = x   + bN * D_DIM + d;
    float*       __restrict__ ob  = out + bN * D_DIM + d;
    const float* __restrict__ smb = sm    + bN * WID;   // wave-uniform rows
    const float* __restrict__ szb = sizev + bN;         // wave-uniform

    // Ring-buffer window: invariant at row n = n0 + t:
    //   W[(t + i) % WID] == x[b, n - CEN + i, d]  (0 if OOB)
    float W[WID];
#pragma unroll
    for (int i = 0; i < WID; ++i) {
        int pos = n0 - CEN + i;
        W[i] = (pos >= 0 && pos < N) ? xb[(size_t)pos * D_DIM] : 0.0f;
    }

#pragma unroll 1
    for (int m = 0; m < CHUNK / WID; ++m) {
#pragma unroll
        for (int jj = 0; jj < WID; ++jj) {           // t % WID == jj (static!)
            const int n = n0 + m * WID + jj;

            if (n < N) {                              // uniform branch (tail block)
                const float* __restrict__ wrow = smb + (size_t)n * WID;

                float acc[4] = {0.f, 0.f, 0.f, 0.f};
#pragma unroll
                for (int i = 0; i < WID; ++i)
                    acc[i & 3] = fmaf(W[(jj + i) % WID], wrow[i], acc[i & 3]);
                float s = (acc[0] + acc[1]) + (acc[2] + acc[3]);

                const float inv = 1.0f / fmaxf(szb[n], 1e-6f);
                ob[(size_t)n * D_DIM] = s * inv;
            }

            // replace oldest element x[n - CEN] (slot jj) with x[n + CEN + 1]
            const int pos = n0 + m * WID + jj + CEN + 1;
            W[jj] = (pos < N) ? xb[(size_t)pos * D_DIM] : 0.0f;
        }
    }
}

extern "C" void kernel_launch(void* const* d_in, const int* in_sizes, int n_in,
                              void* d_out, int out_size, void* d_ws, size_t ws_size,
                              hipStream_t stream) {
    const float* x  = (const float*)d_in[0];
    const float* sz = (const float*)d_in[1];
    const float* sm = (const float*)d_in[2];
    float* out = (float*)d_out;

    const int B = 8;
    const int N = 16384;

    dim3 grid((N + CHUNK - 1) / CHUNK, B, 1);   // 249 x 8
    dim3 block(D_DIM, 1, 1);
    local_enc_kernel<<<grid, block, 0, stream>>>(x, sz, sm, out, N);
}

// Round 3
// 129.740 us; speedup vs baseline: 1.1942x; 1.0108x over previous
//
#include <hip/hip_runtime.h>

#define D_DIM   256
#define WID     33
#define CEN     16
#define CHUNK   66          // 2 * WID — rotation phase repeats per 33 rows

__global__ __launch_bounds__(256) void local_enc_kernel(
    const float* __restrict__ x,
    const float* __restrict__ sizev,
    const float* __restrict__ sm,
    float* __restrict__ out,
    int N)
{
    const int d  = threadIdx.x;          // one column per thread
    const int b  = blockIdx.y;
    const int n0 = blockIdx.x * CHUNK;

    const size_t bN = (size_t)b * (size_t)N;
    const float* __restrict__ xb  = x   + bN * D_DIM + d;
    float*       __restrict__ ob  = out + bN * D_DIM + d;
    const float* __restrict__ smb = sm    + bN * WID;   // wave-uniform rows
    const float* __restrict__ szb = sizev + bN;         // wave-uniform

    // Ring-buffer window, phase invariant at row n = n0 + m*WID + JJ:
    //   W[(JJ + i) % WID] == x[b, n - CEN + i, d]   (0 if OOB)
    float W[WID];
#pragma unroll
    for (int i = 0; i < WID; ++i) {
        int pos = n0 - CEN + i;
        W[i] = (pos >= 0 && pos < N) ? xb[(size_t)pos * D_DIM] : 0.0f;
    }

    // JJ is a LITERAL here -> every W index is a compile-time constant -> VGPRs.
#define ROW_STEP(JJ)                                                          \
    {                                                                         \
        const int n = n0 + mbase + (JJ);                                      \
        if (n < N) {                                                          \
            const float* __restrict__ wrow = smb + (size_t)n * WID;           \
            float a0 = 0.f, a1 = 0.f, a2 = 0.f, a3 = 0.f;                     \
            _Pragma("unroll")                                                 \
            for (int i = 0; i < WID; ++i) {                                   \
                const float xv = W[((JJ) + i) % WID];                         \
                const float wv = wrow[i];                                     \
                if ((i & 3) == 0)      a0 = fmaf(xv, wv, a0);                 \
                else if ((i & 3) == 1) a1 = fmaf(xv, wv, a1);                 \
                else if ((i & 3) == 2) a2 = fmaf(xv, wv, a2);                 \
                else                   a3 = fmaf(xv, wv, a3);                 \
            }                                                                 \
            const float s   = (a0 + a1) + (a2 + a3);                          \
            const float inv = 1.0f / fmaxf(szb[n], 1e-6f);                    \
            ob[(size_t)n * D_DIM] = s * inv;                                  \
        }                                                                     \
        const int pos = n0 + mbase + (JJ) + CEN + 1;                          \
        W[(JJ)] = (pos < N) ? xb[(size_t)pos * D_DIM] : 0.0f;                 \
    }

#pragma unroll 1
    for (int m = 0; m < CHUNK / WID; ++m) {
        const int mbase = m * WID;
        ROW_STEP(0)  ROW_STEP(1)  ROW_STEP(2)  ROW_STEP(3)  ROW_STEP(4)
        ROW_STEP(5)  ROW_STEP(6)  ROW_STEP(7)  ROW_STEP(8)  ROW_STEP(9)
        ROW_STEP(10) ROW_STEP(11) ROW_STEP(12) ROW_STEP(13) ROW_STEP(14)
        ROW_STEP(15) ROW_STEP(16) ROW_STEP(17) ROW_STEP(18) ROW_STEP(19)
        ROW_STEP(20) ROW_STEP(21) ROW_STEP(22) ROW_STEP(23) ROW_STEP(24)
        ROW_STEP(25) ROW_STEP(26) ROW_STEP(27) ROW_STEP(28) ROW_STEP(29)
        ROW_STEP(30) ROW_STEP(31) ROW_STEP(32)
    }
#undef ROW_STEP
}

extern "C" void kernel_launch(void* const* d_in, const int* in_sizes, int n_in,
                              void* d_out, int out_size, void* d_ws, size_t ws_size,
                              hipStream_t stream) {
    const float* x  = (const float*)d_in[0];
    const float* sz = (const float*)d_in[1];
    const float* sm = (const float*)d_in[2];
    float* out = (float*)d_out;

    const int B = 8;
    const int N = 16384;

    dim3 grid((N + CHUNK - 1) / CHUNK, B, 1);   // 249 x 8
    dim3 block(D_DIM, 1, 1);
    local_enc_kernel<<<grid, block, 0, stream>>>(x, sz, sm, out, N);
}

// Round 4
// 127.387 us; speedup vs baseline: 1.2163x; 1.0185x over previous
//
#include <hip/hip_runtime.h>
#include <utility>

#define D_DIM 256
#define WID   33
#define CEN   16
#define RSTR  8                    // rows per strip
#define CHUNK 64                   // rows per block = 8 strips
#define WINW  (RSTR + WID - 1)     // 40-value register window

// All indices below are template/fold constants -> constant GEPs at IR-gen
// time -> SROA promotes W[] and acc[] to VGPRs (rounds 1-3 failed because
// rolled loops left dynamic GEPs at SROA time; VGPR_Count stuck at 28).

template <size_t... Is>
__device__ __forceinline__ void load_win(float (&W)[WINW],
                                         const float* __restrict__ xb,
                                         int base, std::index_sequence<Is...>) {
    ((W[Is] = xb[(size_t)(base + (int)Is) * D_DIM]), ...);
}

template <size_t... Is>
__device__ __forceinline__ void load_win_guard(float (&W)[WINW],
                                               const float* __restrict__ xb,
                                               int base, int N,
                                               std::index_sequence<Is...>) {
    ((W[Is] = (base + (int)Is >= 0 && base + (int)Is < N)
                  ? xb[(size_t)(base + (int)Is) * D_DIM]
                  : 0.0f),
     ...);
}

template <int Rr, size_t... Is>
__device__ __forceinline__ float dot_row(const float (&W)[WINW],
                                         const float* __restrict__ wrow,
                                         std::index_sequence<Is...>) {
    float acc[4] = {0.f, 0.f, 0.f, 0.f};
    ((acc[Is % 4] = fmaf(W[Rr + Is], wrow[Is], acc[Is % 4])), ...);
    return (acc[0] + acc[1]) + (acc[2] + acc[3]);
}

template <int Rr>
__device__ __forceinline__ void process_row(const float (&W)[WINW],
                                            const float* __restrict__ smb,
                                            const float* __restrict__ szb,
                                            float* __restrict__ ob, int nbase) {
    const int n = nbase + Rr;
    const float* __restrict__ wrow = smb + (size_t)n * WID;   // wave-uniform
    const float s = dot_row<Rr>(W, wrow, std::make_index_sequence<WID>{});
    const float inv = 1.0f / fmaxf(szb[n], 1e-6f);
    ob[(size_t)n * D_DIM] = s * inv;
}

__global__ __launch_bounds__(256) void local_enc_kernel(
    const float* __restrict__ x, const float* __restrict__ sizev,
    const float* __restrict__ sm, float* __restrict__ out, int N) {
    const int d  = threadIdx.x;
    const int b  = blockIdx.y;
    const int n0 = blockIdx.x * CHUNK;

    const size_t bN = (size_t)b * (size_t)N;
    const float* __restrict__ xb  = x   + bN * D_DIM + d;
    float*       __restrict__ ob  = out + bN * D_DIM + d;
    const float* __restrict__ smb = sm    + bN * WID;   // wave-uniform
    const float* __restrict__ szb = sizev + bN;         // wave-uniform

    // interior blocks never touch x out of range: min = n0-16, max = n0+CHUNK-1+16
    const bool interior = (n0 >= CEN) && (n0 + CHUNK - 1 + CEN < N);

#pragma unroll 1
    for (int s = 0; s < CHUNK / RSTR; ++s) {
        const int nbase = n0 + s * RSTR;
        float W[WINW];
        if (interior)
            load_win(W, xb, nbase - CEN, std::make_index_sequence<WINW>{});
        else
            load_win_guard(W, xb, nbase - CEN, N, std::make_index_sequence<WINW>{});

        process_row<0>(W, smb, szb, ob, nbase);
        process_row<1>(W, smb, szb, ob, nbase);
        process_row<2>(W, smb, szb, ob, nbase);
        process_row<3>(W, smb, szb, ob, nbase);
        process_row<4>(W, smb, szb, ob, nbase);
        process_row<5>(W, smb, szb, ob, nbase);
        process_row<6>(W, smb, szb, ob, nbase);
        process_row<7>(W, smb, szb, ob, nbase);
    }
}

extern "C" void kernel_launch(void* const* d_in, const int* in_sizes, int n_in,
                              void* d_out, int out_size, void* d_ws, size_t ws_size,
                              hipStream_t stream) {
    const float* x  = (const float*)d_in[0];
    const float* sz = (const float*)d_in[1];
    const float* sm = (const float*)d_in[2];
    float* out = (float*)d_out;

    const int B = 8;
    const int N = 16384;

    dim3 grid(N / CHUNK, B, 1);   // 256 x 8 = 2048 blocks
    dim3 block(D_DIM, 1, 1);
    local_enc_kernel<<<grid, block, 0, stream>>>(x, sz, sm, out, N);
}